// Round 12
// baseline (36661.469 us; speedup 1.0000x reference)
//
#include <hip/hip_runtime.h>
#include <hip/hip_bf16.h>

namespace {
constexpr int kNS = 256, kNA = 8, kNI = 256, kNH = 512;
constexpr int kSeqPerWg = 2;
constexpr int kWgs = 256;                             // 512 sequences / 2
constexpr size_t kOutElems = (size_t)64*kNS*kNA*kNH;  // 33,554,432 main-output elems
}

__device__ __forceinline__ float sigmoid_f(float v) { return 1.0f/(1.0f + __expf(-v)); }
__device__ __forceinline__ float tanh_f(float v) {
    float e = __expf(2.0f*v);            // inf-safe: ->1 / ->-1 at extremes
    return 1.0f - 2.0f/(e + 1.0f);
}

// Exact-fp32 GRU, fp32 OUTPUT (R11 telemetry: d_out is float32 — the bf16
// assumption from R1 was wrong and caused every failure since R2).
// Each wg owns kSeqPerWg whole sequences (seq = b*8+a), h in LDS, zero
// inter-wg communication. VALU dot products, w streamed from L2.
__global__ void __launch_bounds__(256)
gru_exact(const float* __restrict__ x, const void* __restrict__ is_init,
          const float* __restrict__ w_ih, const float* __restrict__ w_hh,
          const float* __restrict__ b_ih, const float* __restrict__ b_hh,
          float* __restrict__ out)
{
    __shared__ float hbuf[kSeqPerWg][kNH];
    __shared__ float xbuf[kSeqPerWg][kNI];
    __shared__ unsigned s_mode;
    const int tid = threadIdx.x;
    const int bx  = blockIdx.x;

    // ---- is_init dtype detection over first 4096 words (16 KB; in-bounds for
    // every candidate width). Signatures:
    //   bf16: words 0x00003F80 / 0x3F803F80 - bf16-only packings
    //   fp32: words {0, 0x3F800000}
    //   uint8/bool: some word >1, none of the above
    //   int32: words {0,1}
    if (tid == 0) s_mode = 0u;
    __syncthreads();
    {
        const unsigned* p = (const unsigned*)is_init;
        unsigned m = 0;
        for (int i = tid; i < 4096; i += 256) {
            unsigned v = p[i];
            if (v == 0x00003F80u || v == 0x3F803F80u) m |= 4u;  // bf16-definite
            else if (v == 0x3F800000u)                m |= 2u;  // fp32 (or bf16 odd)
            else if (v > 1u)                          m |= 1u;  // byte-packed
        }
        if (m) atomicOr(&s_mode, m);
    }
    for (int idx = tid; idx < kSeqPerWg*kNH; idx += 256)
        hbuf[idx >> 9][idx & 511] = 0.f;
    __syncthreads();
    const unsigned mm = s_mode;
    const int fmode = (mm & 4u) ? 3 : (mm & 2u) ? 2 : (mm & 1u) ? 1 : 0;

    const int seq0 = bx * kSeqPerWg;
    float* hn_out = out + kOutElems;

    for (int s = 0; s < kNS; ++s) {
        // ---- stage x rows into LDS (kSeqPerWg x 64 float4) ----
        for (int r4 = tid; r4 < kSeqPerWg*64; r4 += 256) {
            int r = r4 >> 6, i4 = r4 & 63;
            int seq = seq0 + r, b = seq >> 3, a = seq & 7;
            float4 v = *(const float4*)(x + (((size_t)b*kNS + s)*kNA + a)*kNI + i4*4);
            *(float4*)&xbuf[r][i4*4] = v;
        }
        // ---- per-row is_init flags (4-way decode) ----
        int ini[kSeqPerWg];
        #pragma unroll
        for (int r = 0; r < kSeqPerWg; ++r) {
            int b  = (seq0 + r) >> 3;
            int ix = b*kNS + s;
            int v;
            switch (fmode) {
                case 3:  v = ((const unsigned short*)is_init)[ix] != 0; break;  // bf16
                case 2:  v = ((const float*)is_init)[ix] != 0.f;        break;  // fp32
                case 1:  v = ((const unsigned char*)is_init)[ix] != 0;  break;  // uint8
                default: v = ((const int*)is_init)[ix] != 0;            break;  // int32
            }
            ini[r] = v;
        }
        __syncthreads();                        // xbuf ready; prior-step h writes done
        // ---- apply reset: h_t = where(is_init, 0, h) ----
        for (int idx = tid; idx < kSeqPerWg*kNH; idx += 256) {
            int r = idx >> 9;
            if (ini[r]) hbuf[r][idx & 511] = 0.f;
        }
        __syncthreads();

        // ---- gi/gh for this thread's 6 output cols (j = q*256 + tid), all rows ----
        float rz [4][kSeqPerWg];                // q=0..3: gi+gh+biases (r,z gates)
        float gin[2][kSeqPerWg];                // q=4,5: gi_n + b_ih
        float ghn[2][kSeqPerWg];                // q=4,5: gh_n + b_hh
        for (int q = 0; q < 6; ++q) {
            const int j = q*256 + tid;
            const float* wi = w_ih + (size_t)j*kNI;
            const float* wh = w_hh + (size_t)j*kNH;
            float ai[kSeqPerWg], ah[kSeqPerWg];
            #pragma unroll
            for (int r = 0; r < kSeqPerWg; ++r) { ai[r] = 0.f; ah[r] = 0.f; }
            for (int k4 = 0; k4 < kNI/4; ++k4) {
                float4 wv = *(const float4*)(wi + k4*4);
                #pragma unroll
                for (int r = 0; r < kSeqPerWg; ++r) {
                    const float* xr = &xbuf[r][k4*4];
                    ai[r] = fmaf(wv.x, xr[0], ai[r]);
                    ai[r] = fmaf(wv.y, xr[1], ai[r]);
                    ai[r] = fmaf(wv.z, xr[2], ai[r]);
                    ai[r] = fmaf(wv.w, xr[3], ai[r]);
                }
            }
            for (int k4 = 0; k4 < kNH/4; ++k4) {
                float4 wv = *(const float4*)(wh + k4*4);
                #pragma unroll
                for (int r = 0; r < kSeqPerWg; ++r) {
                    const float* hr = &hbuf[r][k4*4];
                    ah[r] = fmaf(wv.x, hr[0], ah[r]);
                    ah[r] = fmaf(wv.y, hr[1], ah[r]);
                    ah[r] = fmaf(wv.z, hr[2], ah[r]);
                    ah[r] = fmaf(wv.w, hr[3], ah[r]);
                }
            }
            const float bi = b_ih[j], bh = b_hh[j];
            if (q < 4) {
                #pragma unroll
                for (int r = 0; r < kSeqPerWg; ++r) rz[q][r] = ai[r] + ah[r] + bi + bh;
            } else {
                #pragma unroll
                for (int r = 0; r < kSeqPerWg; ++r) {
                    gin[q-4][r] = ai[r] + bi;
                    ghn[q-4][r] = ah[r] + bh;
                }
            }
        }
        __syncthreads();                        // all gh reads of hbuf complete

        // ---- gates + update + store fp32 (cols c = tid and tid+256) ----
        #pragma unroll
        for (int p = 0; p < 2; ++p) {
            const int c = tid + p*256;
            #pragma unroll
            for (int r = 0; r < kSeqPerWg; ++r) {
                int seq = seq0 + r, b = seq >> 3, a = seq & 7;
                float rr = sigmoid_f(rz[p][r]);               // r: j = c      (q=p)
                float zz = sigmoid_f(rz[2+p][r]);             // z: j = 512+c  (q=2+p)
                float nn = tanh_f(gin[p][r] + rr*ghn[p][r]);  // n: j = 1024+c (q=4+p)
                float ht = hbuf[r][c];                        // reset-applied h_t
                float hv = (1.f - zz)*nn + zz*ht;
                hbuf[r][c] = hv;
                out[(((size_t)b*kNS + s)*kNA + a)*kNH + c] = hv;
                if (s == kNS-1)
                    hn_out[(size_t)seq*kNH + c] = hv;
            }
        }
        __syncthreads();                        // updates visible before next step
    }
}

extern "C" void kernel_launch(void* const* d_in, const int* in_sizes, int n_in,
                              void* d_out, int out_size, void* d_ws, size_t ws_size,
                              hipStream_t stream) {
    // Input pointers: positional order PROVEN correct by R10 (size-matcher
    // resolved identically); keep the size-based resolver as a no-op safety net.
    const int want[6] = {33554432, 16384, 393216, 786432, 1536, 1536};
    const void* res[6] = {nullptr, nullptr, nullptr, nullptr, nullptr, nullptr};
    bool used[64] = {false};
    for (int k = 0; k < 6; ++k)
        for (int i = 0; i < n_in && i < 64; ++i)
            if (!used[i] && in_sizes[i] == want[k]) { res[k] = d_in[i]; used[i] = true; break; }
    bool ok = true;
    for (int k = 0; k < 6; ++k) if (!res[k]) ok = false;
    if (!ok) for (int k = 0; k < 6; ++k) res[k] = d_in[k];

    const float* x       = (const float*)res[0];
    const void*  is_init = res[1];
    const float* w_ih    = (const float*)res[2];
    const float* w_hh    = (const float*)res[3];
    const float* b_ih    = (const float*)res[4];
    const float* b_hh    = (const float*)res[5];
    float* out = (float*)d_out;      // fp32 output (R11 telemetry evidence)

    gru_exact<<<kWgs, 256, 0, stream>>>(x, is_init, w_ih, w_hh, b_ih, b_hh, out);
}

// Round 13
// 5653.860 us; speedup vs baseline: 6.4843x; 6.4843x over previous
//
#include <hip/hip_runtime.h>
#include <hip/hip_bf16.h>

typedef __attribute__((ext_vector_type(8))) _Float16 half8;
typedef __attribute__((ext_vector_type(4))) float f32x4;

#define MFMA_F16(a,b,c) __builtin_amdgcn_mfma_f32_16x16x32_f16((a),(b),(c),0,0,0)

namespace {
constexpr int kNS = 256, kNA = 8, kNI = 256, kNH = 512;
constexpr size_t kOutElems = (size_t)64*kNS*kNA*kNH;  // 33,554,432
constexpr float kScale = 2048.0f;                     // 2^11 lo-part scaling
constexpr float kInv   = 1.0f/2048.0f;
// LDS byte offsets (fp16): 48 j-rows per array (3 gates x 16 cols)
constexpr int kWihHi = 0;         // 48*512  = 24576
constexpr int kWihLo = 24576;
constexpr int kWhhHi = 49152;     // 48*1024 = 49152
constexpr int kWhhLo = 98304;
constexpr int kSmem  = 147456;    // 147 KB -> 1 wg/CU
constexpr size_t kHPart  = 262144;    // u16 elements per part (512x512)
constexpr size_t kHPhase = 524288;    // hi+lo per phase
}

// Module-scope storage (d_ws unused: size unknown).
__device__ unsigned short g_hbuf[2*kHPhase];   // 2 MB: 2 phases x (hi+lo)
__device__ unsigned int   g_cnt[512];          // 8 groups, stride 64
__device__ int            g_mode;              // is_init dtype

__device__ __forceinline__ float sigmoid_f(float v) { return 1.0f/(1.0f + __expf(-v)); }
__device__ __forceinline__ float tanh_f(float v) {
    float e = __expf(2.0f*v);
    return 1.0f - 2.0f/(e + 1.0f);
}
__device__ __forceinline__ void split2(float v, unsigned short& hi, unsigned short& lo) {
    _Float16 h = (_Float16)v;
    _Float16 l = (_Float16)((v - (float)h) * kScale);
    hi = __builtin_bit_cast(unsigned short, h);
    lo = __builtin_bit_cast(unsigned short, l);
}

// Prep (1 block): zero barrier counters; detect is_init dtype (4-way).
__global__ void gru_prep(const unsigned int* __restrict__ is_init_raw) {
    for (int i = threadIdx.x; i < 512; i += 256) g_cnt[i] = 0u;
    if (threadIdx.x == 0) g_mode = 0;
    __syncthreads();
    unsigned m = 0;
    for (int i = threadIdx.x; i < 4096; i += 256) {
        unsigned v = is_init_raw[i];
        if (v == 0x00003F80u || v == 0x3F803F80u) m |= 4u;  // bf16-definite
        else if (v == 0x3F800000u)                m |= 2u;  // fp32
        else if (v > 1u)                          m |= 1u;  // byte-packed
    }
    if (m) atomicOr(&g_mode, (int)m);
}

// Persistent GRU (R5/R6 machinery, proven by R12 forensics + pass), fp32 OUT.
// 256 wgs x 256 thr; 147 KB LDS -> 1 wg/CU. mi = bx&7: 8 groups x 64 seq-rows
// (32 wgs/group, same XCD under round-robin). ci = bx>>3: 32 col-blocks x 16.
// fp16 double-split operands (eff 2^-22), fp32 accum + fp32 master h.
__global__ void __launch_bounds__(256, 1)
gru_main(const float* __restrict__ x, const void* __restrict__ is_init,
         const float* __restrict__ w_ih, const float* __restrict__ w_hh,
         const float* __restrict__ b_ih, const float* __restrict__ b_hh,
         float* __restrict__ out)
{
    extern __shared__ char smem[];
    const int tid = threadIdx.x;
    const int bx  = blockIdx.x;
    const int mi  = bx & 7;
    const int ci  = bx >> 3;
    const int c0  = ci * 16;

    // ---- stage split weight slices into LDS (swizzle on FULL byte offset) ----
    for (int idx = tid; idx < 3072; idx += 256) {           // w_ih: 48 rows x 64 float4
        int jr = idx >> 6, q = idx & 63;
        int j = (jr >> 4)*kNH + c0 + (jr & 15);
        float4 v = *(const float4*)(w_ih + (size_t)j*kNI + q*4);
        ushort4 hi, lo;
        split2(v.x, hi.x, lo.x); split2(v.y, hi.y, lo.y);
        split2(v.z, hi.z, lo.z); split2(v.w, hi.w, lo.w);
        unsigned off = ((unsigned)(jr*512 + q*8)) ^ ((unsigned)(jr & 7) << 4);
        *(ushort4*)(smem + kWihHi + off) = hi;
        *(ushort4*)(smem + kWihLo + off) = lo;
    }
    for (int idx = tid; idx < 6144; idx += 256) {           // w_hh: 48 rows x 128 float4
        int jr = idx >> 7, q = idx & 127;
        int j = (jr >> 4)*kNH + c0 + (jr & 15);
        float4 v = *(const float4*)(w_hh + (size_t)j*kNH + q*4);
        ushort4 hi, lo;
        split2(v.x, hi.x, lo.x); split2(v.y, hi.y, lo.y);
        split2(v.z, hi.z, lo.z); split2(v.w, hi.w, lo.w);
        unsigned off = ((unsigned)(jr*1024 + q*8)) ^ ((unsigned)(jr & 7) << 4);
        *(ushort4*)(smem + kWhhHi + off) = hi;
        *(ushort4*)(smem + kWhhLo + off) = lo;
    }
    __syncthreads();

    const int fm = g_mode;              // 0 int32, 1 byte, 2 fp32, 4 bf16
    const int fmode = (fm & 4) ? 3 : (fm & 2) ? 2 : (fm & 1) ? 1 : 0;

    const int l    = tid & 63, w = tid >> 6;
    const int lrow = l & 15, kgrp = l >> 4;

    const int cE = c0 + lrow;                 // this lane's output column
    const int mA = mi*64 + w*16 + lrow;       // A-fragment row (seq index)
    const int bA = mA >> 3;
    const size_t xrow0 = ((size_t)bA*(kNS*kNA) + (mA & 7))*kNI + kgrp*8;
    const int hoffA = mA*kNH + kgrp*8;        // within an hbuf part

    const unsigned swzb = (unsigned)(lrow & 7) << 4;
    unsigned wihB[3], whhB[3];
    #pragma unroll
    for (int g = 0; g < 3; ++g) {
        wihB[g] = (unsigned)((g*16 + lrow)*512  + kgrp*16);
        whhB[g] = (unsigned)((g*16 + lrow)*1024 + kgrp*16);
    }

    const float biasR  = b_ih[cE]        + b_hh[cE];
    const float biasZ  = b_ih[kNH + cE]  + b_hh[kNH + cE];
    const float biasIN = b_ih[2*kNH + cE];
    const float biasHN = b_hh[2*kNH + cE];
    const int mE0 = mi*64 + w*16 + kgrp*4;    // C/D row base (seq index)
    const int bE  = mE0 >> 3, aE0 = mE0 & 7;

    unsigned int* cnt = &g_cnt[mi*64];
    float hreg[4] = {0.f, 0.f, 0.f, 0.f};
    float* hn_out = out + kOutElems;
    int dead = 0;

#define LOADX(dh, dl, ss) do {                                                     \
        const float* xr_ = x + xrow0 + (size_t)(ss)*(kNA*kNI);                     \
        _Pragma("unroll")                                                          \
        for (int kb_ = 0; kb_ < 8; ++kb_) {                                        \
            float4 v0_ = *(const float4*)(xr_ + kb_*32);                           \
            float4 v1_ = *(const float4*)(xr_ + kb_*32 + 4);                       \
            float vv_[8] = {v0_.x,v0_.y,v0_.z,v0_.w,v1_.x,v1_.y,v1_.z,v1_.w};      \
            half8 th_, tl_;                                                        \
            _Pragma("unroll")                                                      \
            for (int e_ = 0; e_ < 8; ++e_) {                                       \
                _Float16 h_ = (_Float16)vv_[e_];                                   \
                th_[e_] = h_;                                                      \
                tl_[e_] = (_Float16)((vv_[e_] - (float)h_) * kScale);              \
            }                                                                      \
            dh[kb_] = th_; dl[kb_] = tl_;                                          \
        }                                                                          \
    } while (0)

    half8 xfh[8], xfl[8], xnh[8], xnl[8];
    LOADX(xfh, xfl, 0);

    for (int s = 0; s < kNS; ++s) {
        const int ii = bA*kNS + s;
        const int ie = bE*kNS + s;
        int iniA, iniE;
        switch (fmode) {
            case 3:  iniA = ((const unsigned short*)is_init)[ii] != 0;
                     iniE = ((const unsigned short*)is_init)[ie] != 0; break;
            case 2:  iniA = ((const float*)is_init)[ii] != 0.f;
                     iniE = ((const float*)is_init)[ie] != 0.f;       break;
            case 1:  iniA = ((const unsigned char*)is_init)[ii] != 0;
                     iniE = ((const unsigned char*)is_init)[ie] != 0; break;
            default: iniA = ((const int*)is_init)[ii] != 0;
                     iniE = ((const int*)is_init)[ie] != 0;           break;
        }
        f32x4 aR = {0,0,0,0}, aZ = {0,0,0,0}, aGN = {0,0,0,0}, aHN = {0,0,0,0};
        f32x4 lR = {0,0,0,0}, lZ = {0,0,0,0}, lGN = {0,0,0,0}, lHN = {0,0,0,0};

        // ---- gi = x @ w_ih^T (3-pass split; independent of h) ----
        #pragma unroll
        for (int kb = 0; kb < 8; ++kb) {
            {   half8 bhi = *(const half8*)(smem + kWihHi + ((wihB[0] + kb*64) ^ swzb));
                half8 blo = *(const half8*)(smem + kWihLo + ((wihB[0] + kb*64) ^ swzb));
                aR = MFMA_F16(xfh[kb], bhi, aR);
                lR = MFMA_F16(xfl[kb], bhi, lR);
                lR = MFMA_F16(xfh[kb], blo, lR); }
            {   half8 bhi = *(const half8*)(smem + kWihHi + ((wihB[1] + kb*64) ^ swzb));
                half8 blo = *(const half8*)(smem + kWihLo + ((wihB[1] + kb*64) ^ swzb));
                aZ = MFMA_F16(xfh[kb], bhi, aZ);
                lZ = MFMA_F16(xfl[kb], bhi, lZ);
                lZ = MFMA_F16(xfh[kb], blo, lZ); }
            {   half8 bhi = *(const half8*)(smem + kWihHi + ((wihB[2] + kb*64) ^ swzb));
                half8 blo = *(const half8*)(smem + kWihLo + ((wihB[2] + kb*64) ^ swzb));
                aGN = MFMA_F16(xfh[kb], bhi, aGN);
                lGN = MFMA_F16(xfl[kb], bhi, lGN);
                lGN = MFMA_F16(xfh[kb], blo, lGN); }
        }

        // prefetch next step's x fragments (completes during barrier spin)
        if (s + 1 < kNS) LOADX(xnh, xnl, s + 1);

        // ---- wait for h(s): 32-wg subset barrier (latched bailout) ----
        if (s > 0) {
            if (tid == 0 && !dead) {
                const unsigned target = (unsigned)(32*s);
                long it = 0;
                while (__hip_atomic_load(cnt, __ATOMIC_ACQUIRE, __HIP_MEMORY_SCOPE_AGENT) < target) {
                    if (++it > 50000000L) { dead = 1; break; }
                    __builtin_amdgcn_s_sleep(2);
                }
            }
            __syncthreads();
            const unsigned short* hb = g_hbuf + (size_t)(s & 1)*kHPhase;
            const half8 zz = {};
            #pragma unroll
            for (int kb = 0; kb < 16; ++kb) {
                half8 ahi = *(const half8*)(hb + hoffA + kb*32);
                half8 alo = *(const half8*)(hb + kHPart + hoffA + kb*32);
                ahi = iniA ? zz : ahi;      // h_t = where(is_init, 0, h)
                alo = iniA ? zz : alo;
                {   half8 bhi = *(const half8*)(smem + kWhhHi + ((whhB[0] + kb*64) ^ swzb));
                    half8 blo = *(const half8*)(smem + kWhhLo + ((whhB[0] + kb*64) ^ swzb));
                    aR = MFMA_F16(ahi, bhi, aR);
                    lR = MFMA_F16(alo, bhi, lR);
                    lR = MFMA_F16(ahi, blo, lR); }
                {   half8 bhi = *(const half8*)(smem + kWhhHi + ((whhB[1] + kb*64) ^ swzb));
                    half8 blo = *(const half8*)(smem + kWhhLo + ((whhB[1] + kb*64) ^ swzb));
                    aZ = MFMA_F16(ahi, bhi, aZ);
                    lZ = MFMA_F16(alo, bhi, lZ);
                    lZ = MFMA_F16(ahi, blo, lZ); }
                {   half8 bhi = *(const half8*)(smem + kWhhHi + ((whhB[2] + kb*64) ^ swzb));
                    half8 blo = *(const half8*)(smem + kWhhLo + ((whhB[2] + kb*64) ^ swzb));
                    aHN = MFMA_F16(ahi, bhi, aHN);
                    lHN = MFMA_F16(alo, bhi, lHN);
                    lHN = MFMA_F16(ahi, blo, lHN); }
            }
        }

        // ---- gates + state update (fp32) + fp32 stores ----
        unsigned short* ho_hi = g_hbuf + (size_t)((s+1) & 1)*kHPhase;
        unsigned short* ho_lo = ho_hi + kHPart;
        const size_t obase = ((size_t)bE*(kNS*kNA) + (size_t)s*kNA + aE0)*kNH + cE;
        #pragma unroll
        for (int i = 0; i < 4; ++i) {
            float pr  = aR[i]  + lR[i]*kInv  + biasR;
            float pz  = aZ[i]  + lZ[i]*kInv  + biasZ;
            float gin = aGN[i] + lGN[i]*kInv + biasIN;
            float ghn = aHN[i] + lHN[i]*kInv + biasHN;
            float htv = iniE ? 0.f : hreg[i];
            float r  = sigmoid_f(pr);
            float zg = sigmoid_f(pz);
            float nn = tanh_f(gin + r*ghn);
            float hv = (1.f - zg)*nn + zg*htv;
            hreg[i] = hv;
            out[obase + (size_t)i*kNH] = hv;          // fp32 (R12-proven dtype)
            unsigned short shi, slo;
            split2(hv, shi, slo);
            ho_hi[(mE0 + i)*kNH + cE] = shi;
            ho_lo[(mE0 + i)*kNH + cE] = slo;
        }
        if (s == kNS-1) {
            #pragma unroll
            for (int i = 0; i < 4; ++i)
                hn_out[(size_t)(mE0 + i)*kNH + cE] = hreg[i];
        }

        // ---- publish h(s+1) ----
        if (s < kNS-1) {
            __syncthreads();     // all waves drain vmcnt before s_barrier
            if (tid == 0) {
                __threadfence();
                __hip_atomic_fetch_add(cnt, 1u, __ATOMIC_RELEASE, __HIP_MEMORY_SCOPE_AGENT);
            }
            #pragma unroll
            for (int i = 0; i < 8; ++i) { xfh[i] = xnh[i]; xfl[i] = xnl[i]; }
        }
    }
#undef LOADX
}

extern "C" void kernel_launch(void* const* d_in, const int* in_sizes, int n_in,
                              void* d_out, int out_size, void* d_ws, size_t ws_size,
                              hipStream_t stream) {
    // Size-based resolver (no-op safety net; positional order proven in R10).
    const int want[6] = {33554432, 16384, 393216, 786432, 1536, 1536};
    const void* res[6] = {nullptr, nullptr, nullptr, nullptr, nullptr, nullptr};
    bool used[64] = {false};
    for (int k = 0; k < 6; ++k)
        for (int i = 0; i < n_in && i < 64; ++i)
            if (!used[i] && in_sizes[i] == want[k]) { res[k] = d_in[i]; used[i] = true; break; }
    bool ok = true;
    for (int k = 0; k < 6; ++k) if (!res[k]) ok = false;
    if (!ok) for (int k = 0; k < 6; ++k) res[k] = d_in[k];

    const float* x       = (const float*)res[0];
    const void*  is_init = res[1];
    const float* w_ih    = (const float*)res[2];
    const float* w_hh    = (const float*)res[3];
    const float* b_ih    = (const float*)res[4];
    const float* b_hh    = (const float*)res[5];
    float* out = (float*)d_out;      // fp32 output (R12-proven)

    gru_prep<<<1, 256, 0, stream>>>((const unsigned int*)is_init);

    hipFuncSetAttribute((const void*)gru_main,
                        hipFuncAttributeMaxDynamicSharedMemorySize, kSmem);
    gru_main<<<256, 256, kSmem, stream>>>(x, is_init, w_ih, w_hh, b_ih, b_hh, out);
}